// Round 21
// baseline (58.112 us; speedup 1.0000x reference)
//
#include <hip/hip_runtime.h>
#include <hip/hip_bf16.h>
#include <cstddef>
#include <cstdint>

#define B_ 2
#define C_ 512
#define L_ 1024
#define NH_ 8
#define HD_ 64
#define OC_ 1536  // 3*C

typedef short short8 __attribute__((ext_vector_type(8)));
typedef short short4v __attribute__((ext_vector_type(4)));
typedef float f32x4 __attribute__((ext_vector_type(4)));
typedef __fp16 f16x4 __attribute__((ext_vector_type(4)));
typedef __fp16 f16x2 __attribute__((ext_vector_type(2)));

__device__ inline float bf_bits_to_f32(unsigned short u) {
  union { unsigned u32; float f; } c; c.u32 = ((unsigned)u) << 16; return c.f;
}
__device__ inline short f32_to_bf_bits(float f) {
  union { float f; unsigned u; } c; c.f = f;
  return (short)((c.u + 0x7FFFu + ((c.u >> 16) & 1u)) >> 16);
}

// Fast 2^y on the VALU (Schraudolph; r18-verified at absmax 0.031).
__device__ __forceinline__ float fexp2_fast(float y) {
  union { unsigned u; float f; } v;
  v.u = (unsigned)fmaf(y, 8388608.0f, 1065055000.0f);
  return v.f;
}

// async global->LDS, 16B per lane; LDS dest = wave-uniform base + lane*16.
__device__ __forceinline__ void gl2lds16(const short* g, short* l) {
  __builtin_amdgcn_global_load_lds(
      (const __attribute__((address_space(1))) unsigned*)(const void*)g,
      (__attribute__((address_space(3))) unsigned*)(void*)l, 16, 0, 0);
}

// ---------------------------------------------------------------------------
// K1 prep: blocks 0-511: BN stats -> s,t. 512-703: w_qkv -> bf16.
//          704-767: w_proj permuted cols -> bf16 (wpp[o][d*8+g]).
// ---------------------------------------------------------------------------
__global__ __launch_bounds__(256) void prep_kernel(
    const float* __restrict__ x, const float* __restrict__ gamma,
    const float* __restrict__ beta, const float* __restrict__ w_qkv,
    const float* __restrict__ w_proj,
    float* __restrict__ s_out, float* __restrict__ t_out,
    short* __restrict__ wq16, short* __restrict__ wpp16)
{
  const int bid = blockIdx.x;
  const int tid = threadIdx.x;
  if (bid < 512) {
    const int ch = bid;
    const float4 v0 = *(const float4*)(x + (size_t)ch * L_ + tid * 4);
    const float4 v1 = *(const float4*)(x + (size_t)(C_ + ch) * L_ + tid * 4);
    float s1 = v0.x + v0.y + v0.z + v0.w + v1.x + v1.y + v1.z + v1.w;
    float s2 = v0.x*v0.x + v0.y*v0.y + v0.z*v0.z + v0.w*v0.w
             + v1.x*v1.x + v1.y*v1.y + v1.z*v1.z + v1.w*v1.w;
    #pragma unroll
    for (int off = 32; off > 0; off >>= 1) {
      s1 += __shfl_down(s1, off);
      s2 += __shfl_down(s2, off);
    }
    __shared__ float r1[4], r2[4];
    const int wid = tid >> 6, lane = tid & 63;
    if (lane == 0) { r1[wid] = s1; r2[wid] = s2; }
    __syncthreads();
    if (tid == 0) {
      const float S1 = r1[0] + r1[1] + r1[2] + r1[3];
      const float S2 = r2[0] + r2[1] + r2[2] + r2[3];
      const float invN = 1.f / (float)(B_ * L_);
      const float mean = S1 * invN;
      const float var  = S2 * invN - mean * mean;  // biased
      const float rstd = rsqrtf(var + 1e-5f);
      const float sc = gamma[ch] * rstd;
      s_out[ch] = sc;
      t_out[ch] = beta[ch] - mean * sc;
    }
  } else if (bid < 704) {
    const int base = (bid - 512) * 4096 + tid * 16;
    #pragma unroll
    for (int it = 0; it < 2; ++it) {
      const float4 a0 = *(const float4*)(w_qkv + base + it * 8);
      const float4 a1 = *(const float4*)(w_qkv + base + it * 8 + 4);
      short8 v;
      v[0] = f32_to_bf_bits(a0.x); v[1] = f32_to_bf_bits(a0.y);
      v[2] = f32_to_bf_bits(a0.z); v[3] = f32_to_bf_bits(a0.w);
      v[4] = f32_to_bf_bits(a1.x); v[5] = f32_to_bf_bits(a1.y);
      v[6] = f32_to_bf_bits(a1.z); v[7] = f32_to_bf_bits(a1.w);
      *(short8*)(wq16 + base + it * 8) = v;
    }
  } else {
    // wpp[o][c'] = w[o][(c'&7)*64+(c'>>3)]
    #pragma unroll
    for (int grp = 0; grp < 4; ++grp) {
      const int idx = (bid - 704) * 4096 + tid * 16 + grp * 4;
      const int o = idx >> 9, cp = idx & 511;
      short4v v;
      #pragma unroll
      for (int j = 0; j < 4; ++j) {
        const int c = ((cp + j) & 7) * 64 + ((cp + j) >> 3);
        v[j] = f32_to_bf_bits(w_proj[(size_t)o * C_ + c]);
      }
      *(short4v*)(wpp16 + (size_t)o * C_ + cp) = v;
    }
  }
}

// ---------------------------------------------------------------------------
// K2: xT[b][t][c] = bf16(x[b][c][t]*s[c] + t[c])  (BN folded into transpose)
// ---------------------------------------------------------------------------
__global__ __launch_bounds__(256) void xt_kernel(
    const float* __restrict__ x, const float* __restrict__ s,
    const float* __restrict__ t, short* __restrict__ xT)
{
  __shared__ float T[64][65];
  const int t0 = blockIdx.x * 64, c0 = blockIdx.y * 64, b = blockIdx.z;
  const int tid = threadIdx.x;
  const float* xp = x + (size_t)b * C_ * L_;
  #pragma unroll
  for (int it = 0; it < 4; ++it) {
    const int idx = it * 256 + tid;
    const int rr = idx >> 4, c4 = (idx & 15) * 4;  // rr = c-local, c4 = t-local
    const float4 v = *(const float4*)(xp + (size_t)(c0 + rr) * L_ + t0 + c4);
    const float sc = s[c0 + rr], tc = t[c0 + rr];
    T[rr][c4 + 0] = fmaf(v.x, sc, tc);
    T[rr][c4 + 1] = fmaf(v.y, sc, tc);
    T[rr][c4 + 2] = fmaf(v.z, sc, tc);
    T[rr][c4 + 3] = fmaf(v.w, sc, tc);
  }
  __syncthreads();
  #pragma unroll
  for (int it = 0; it < 4; ++it) {
    const int idx = it * 256 + tid;
    const int tt_ = idx >> 4, cc4 = (idx & 15) * 4;
    short4v o;
    #pragma unroll
    for (int j = 0; j < 4; ++j) o[j] = f32_to_bf_bits(T[cc4 + j][tt_]);
    *(short4v*)(xT + ((size_t)b * L_ + t0 + tt_) * C_ + c0 + cc4) = o;
  }
}

// ---------------------------------------------------------------------------
// K3: bf16 MFMA GEMM, both operands row-major shared-K (r12 verbatim).
// ---------------------------------------------------------------------------
template <int MR, int NR, bool OUT_BF16>
__global__ __launch_bounds__(256) void gemm_bt16_kernel(
    const short* __restrict__ A, const short* __restrict__ B,
    const float* __restrict__ bias, const float* __restrict__ res,
    void* __restrict__ Cv, int M, int N, int K,
    size_t sB, size_t sC, size_t sR)
{
  constexpr int BM = MR * 32, BN = NR * 32;
  __shared__ short As[BM * 64];
  __shared__ short Bs[BN * 64];
  const int tid = threadIdx.x;
  const int l = tid & 63, w = tid >> 6;
  const int wr = w >> 1, wc = w & 1;
  const int ll = l & 15;
  const int n0 = blockIdx.x * BN, m0 = blockIdx.y * BM, bz = blockIdx.z;
  const short* Bg = B + (size_t)bz * sB;
  f32x4 acc[MR][NR] = {};

  for (int k0 = 0; k0 < K; k0 += 64) {
    #pragma unroll
    for (int it = 0; it < BM / 32; ++it) {
      const int row0 = w * (BM / 4) + it * 8;
      const int row = row0 + (l >> 3), sl = l & 7;
      gl2lds16(A + (size_t)(m0 + row) * K + k0 + ((sl ^ (row & 7)) * 8),
               As + row0 * 64);
    }
    #pragma unroll
    for (int it = 0; it < BN / 32; ++it) {
      const int row0 = w * (BN / 4) + it * 8;
      const int row = row0 + (l >> 3), sl = l & 7;
      gl2lds16(Bg + (size_t)(n0 + row) * K + k0 + ((sl ^ (row & 7)) * 8),
               Bs + row0 * 64);
    }
    __syncthreads();
    #pragma unroll
    for (int kk = 0; kk < 2; ++kk) {
      short8 af[MR], bfg[NR];
      const int sd = kk * 4 + (l >> 4);
      #pragma unroll
      for (int m = 0; m < MR; ++m) {
        const int ra = wr * MR * 16 + m * 16 + ll;
        af[m] = *(const short8*)(As + ra * 64 + (sd ^ (ra & 7)) * 8);
      }
      #pragma unroll
      for (int n = 0; n < NR; ++n) {
        const int rb = wc * NR * 16 + n * 16 + ll;
        bfg[n] = *(const short8*)(Bs + rb * 64 + (sd ^ (rb & 7)) * 8);
      }
      #pragma unroll
      for (int m = 0; m < MR; ++m)
        #pragma unroll
        for (int n = 0; n < NR; ++n)
          acc[m][n] = __builtin_amdgcn_mfma_f32_16x16x32_bf16(
              af[m], bfg[n], acc[m][n], 0, 0, 0);
    }
    __syncthreads();
  }

  const int rg4 = (l >> 4) * 4;
  __hip_bfloat16* Cb = (__hip_bfloat16*)Cv + (size_t)bz * sC;
  float* Cf = (float*)Cv + (size_t)bz * sC;
  const float* Rp = res + (size_t)bz * sR;
  #pragma unroll
  for (int m = 0; m < MR; ++m) {
    #pragma unroll
    for (int reg = 0; reg < 4; ++reg) {
      const int gm = m0 + wr * MR * 16 + m * 16 + rg4 + reg;
      const float bv = bias[gm];
      #pragma unroll
      for (int n = 0; n < NR; ++n) {
        const int gn = n0 + wc * NR * 16 + n * 16 + ll;
        float v = acc[m][n][reg] + bv;
        if (OUT_BF16) {
          Cb[(size_t)gm * N + gn] = __hip_bfloat16_raw{(unsigned short)f32_to_bf_bits(v)};
        } else {
          v += Rp[(size_t)gm * N + gn];
          Cf[(size_t)gm * N + gn] = v;
        }
      }
    }
  }
}

// ---------------------------------------------------------------------------
// K4: MFMA attention — r18 structure, but the c-loop is ROLLED (unroll 1).
// The fully-unrolled 128-iteration body was ~3000 inst (~25 KB of code);
// gfx950 L1 I$ is ~32 KB, and 16 streaming waves/CU thrash it — the one
// mechanism consistent with five null data-path experiments (diet, PV
// chains, exp pipe, occupancy, staging). Rolled body ~400 inst (~3 KB).
// ---------------------------------------------------------------------------
__global__ __launch_bounds__(256, 4) void attn_kernel(
    const __hip_bfloat16* __restrict__ qkv, short* __restrict__ hT)
{
  __shared__ __fp16 Klds[1024 * 8];   // [f][g] f16, 16 KB (reused for O out)
  __shared__ __fp16 Vlds[9 * 1032];   // [9][1032] f16, padded rows

  const int tq = blockIdx.x, d = blockIdx.y, b = blockIdx.z;
  const int tid = threadIdx.x;
  const int w = tid >> 6, l = tid & 63;
  const int hi = l >> 4, ll = l & 15;
  const int t0 = tq * 128 + w * 32;
  const short* base = (const short*)qkv + (size_t)b * OC_ * L_;
  short* KldsS = (short*)Klds;
  short* VldsS = (short*)Vlds;

  // ---- stage K[f][g] as f16 (coalesced along f)
  #pragma unroll
  for (int it = 0; it < 4; ++it) {
    const int f = it * 256 + tid;
    unsigned u[4];
    #pragma unroll
    for (int e = 0; e < 4; ++e) {
      const f16x2 p = __builtin_amdgcn_cvt_pkrtz(
          bf_bits_to_f32((unsigned short)base[(size_t)((8 + 2*e)   * HD_ + d) * L_ + f]),
          bf_bits_to_f32((unsigned short)base[(size_t)((8 + 2*e+1) * HD_ + d) * L_ + f]));
      u[e] = __builtin_bit_cast(unsigned, p);
    }
    uint4 uu; uu.x = u[0]; uu.y = u[1]; uu.z = u[2]; uu.w = u[3];
    *(uint4*)(KldsS + f * 8) = uu;
  }
  // ---- stage V[g][f] as f16, padded rows (no swizzle)
  #pragma unroll
  for (int it = 0; it < 4; ++it) {
    const int i = it * 256 + tid;
    const int g = i >> 7, fs = i & 127;
    const short8 v = *(const short8*)(
        base + (size_t)((16 + g) * HD_ + d) * L_ + fs * 8);
    unsigned u[4];
    #pragma unroll
    for (int e = 0; e < 4; ++e) {
      const f16x2 p = __builtin_amdgcn_cvt_pkrtz(
          bf_bits_to_f32((unsigned short)v[2 * e]),
          bf_bits_to_f32((unsigned short)v[2 * e + 1]));
      u[e] = __builtin_bit_cast(unsigned, p);
    }
    uint4 uu; uu.x = u[0]; uu.y = u[1]; uu.z = u[2]; uu.w = u[3];
    *(uint4*)(VldsS + g * 1032 + fs * 8) = uu;
  }
  // ---- row 8 = ones (f16 1.0 = 0x3C00): denominator via MFMA
  {
    uint2 ones; ones.x = 0x3C003C00u; ones.y = 0x3C003C00u;
    *(uint2*)(VldsS + 8 * 1032 + tid * 4) = ones;
  }

  // ---- Q B-fragments (lanes l<32): B[k=4*hi+j][t], scale*log2e folded in
  f16x4 bQ[2] = {};
  if (l < 32) {
    const int g0 = 4 * hi;  // hi in {0,1}
    #pragma unroll
    for (int tt = 0; tt < 2; ++tt) {
      const int t = t0 + tt * 16 + ll;
      float q[4];
      #pragma unroll
      for (int j = 0; j < 4; ++j)
        q[j] = bf_bits_to_f32(
                   (unsigned short)base[(size_t)((g0 + j) * HD_ + d) * L_ + t]) *
               0.29448889f;  // 24^-0.5 * log2(e)
      const f16x2 a = __builtin_amdgcn_cvt_pkrtz(q[0], q[1]);
      const f16x2 bb = __builtin_amdgcn_cvt_pkrtz(q[2], q[3]);
      union { f16x4 v; uint2 u; } m;
      m.u.x = __builtin_bit_cast(unsigned, a);
      m.u.y = __builtin_bit_cast(unsigned, bb);
      bQ[tt] = m.v;
    }
  }

  __syncthreads();  // K/V staged

  const int vrow = (ll < 9) ? ll : 8;     // lane-constant PV A-row
  const f32x4 z4 = {0.f, 0.f, 0.f, 0.f};
  f32x4 accA[2] = {}, accB[2] = {};       // two independent PV chains per tt
  const __fp16* akB = Klds + ll * 8 + 4 * (hi & 1);
  const __fp16* avB = Vlds + vrow * 1032 + 4 * hi;

  #pragma unroll 1   // ROLLED: keep the body I$-resident (~3 KB, was ~25 KB)
  for (int c = 0; c < 8; ++c) {
    const __fp16* akC = akB + c * 1024;
    const __fp16* avC = avB + c * 128;
    #pragma unroll
    for (int ft = 0; ft < 8; ++ft) {
      const f16x4 ak = *(const f16x4*)(akC + ft * 128);
      const f16x4 av = *(const f16x4*)(avC + ft * 16);
      #pragma unroll
      for (int tt = 0; tt < 2; ++tt) {
        const f32x4 s = __builtin_amdgcn_mfma_f32_16x16x16f16(
            ak, bQ[tt], z4, 0, 0, 0);
        const f16x2 p0 = __builtin_amdgcn_cvt_pkrtz(fexp2_fast(s[0]),
                                                    fexp2_fast(s[1]));
        const f16x2 p1 = __builtin_amdgcn_cvt_pkrtz(fexp2_fast(s[2]),
                                                    fexp2_fast(s[3]));
        union { f16x4 v; uint2 u; } bp;
        bp.u.x = __builtin_bit_cast(unsigned, p0);
        bp.u.y = __builtin_bit_cast(unsigned, p1);
        if (c & 1)
          accB[tt] = __builtin_amdgcn_mfma_f32_16x16x16f16(av, bp.v, accB[tt], 0, 0, 0);
        else
          accA[tt] = __builtin_amdgcn_mfma_f32_16x16x16f16(av, bp.v, accA[tt], 0, 0, 0);
      }
    }
  }

  // ---- epilogue: D row 8 (lane 32+ll, reg 0) = denominator; O out via LDS
  f32x4 accO[2];
  #pragma unroll
  for (int tt = 0; tt < 2; ++tt) accO[tt] = accA[tt] + accB[tt];

  __syncthreads();                 // all waves done with Klds
  short* Olds = KldsS;             // [128][8]
  #pragma unroll
  for (int nt = 0; nt < 2; ++nt) {
    const float sum = __shfl(accO[nt][0], 32 + ll);
    const float inv = 1.f / sum;
    if (hi < 2) {
      const int tl = w * 32 + nt * 16 + ll;
      #pragma unroll
      for (int reg = 0; reg < 4; ++reg)
        Olds[tl * 8 + hi * 4 + reg] = f32_to_bf_bits(accO[nt][reg] * inv);
    }
  }
  __syncthreads();
  if (tid < 128) {
    const short8 ov = *(const short8*)(Olds + tid * 8);
    *(short8*)(hT + ((size_t)b * L_ + tq * 128 + tid) * C_ + d * 8) = ov;
  }
}

// ---------------------------------------------------------------------------
extern "C" void kernel_launch(void* const* d_in, const int* in_sizes, int n_in,
                              void* d_out, int out_size, void* d_ws, size_t ws_size,
                              hipStream_t stream) {
  (void)in_sizes; (void)n_in; (void)out_size; (void)ws_size;
  const float* x      = (const float*)d_in[0];
  const float* gamma  = (const float*)d_in[1];
  const float* beta   = (const float*)d_in[2];
  const float* w_qkv  = (const float*)d_in[3];
  const float* b_qkv  = (const float*)d_in[4];
  const float* w_proj = (const float*)d_in[5];
  const float* b_proj = (const float*)d_in[6];
  float* out = (float*)d_out;
  char* wsb = (char*)d_ws;

  // workspace layout (bytes), ~12 MB
  float* s_buf = (float*)(wsb + 0);                         // 2 KB
  float* t_buf = (float*)(wsb + 2048);                      // 2 KB
  short* wq16  = (short*)(wsb + 4096);                      // 1.5 MB
  short* wpp16 = (short*)(wsb + 4096 + 1572864);            // 0.5 MB
  short* xT    = (short*)(wsb + 4096 + 2097152);            // 2 MB
  short* qkv   = (short*)(wsb + 4096 + 4194304);            // 6 MB
  short* hT    = (short*)(wsb + 4096 + 10485760);           // 2 MB

  hipLaunchKernelGGL(prep_kernel, dim3(768), dim3(256), 0, stream,
                     x, gamma, beta, w_qkv, w_proj, s_buf, t_buf, wq16, wpp16);
  hipLaunchKernelGGL(xt_kernel, dim3(L_ / 64, C_ / 64, B_), dim3(256), 0, stream,
                     x, s_buf, t_buf, xT);
  // qkv[o][t] = wq16 @ xn + b_qkv   (64x64 tiles, 768 blocks = 3/CU)
  hipLaunchKernelGGL((gemm_bt16_kernel<2, 2, true>),
                     dim3(L_ / 64, OC_ / 64, B_), dim3(256), 0, stream,
                     wq16, xT, b_qkv, (const float*)nullptr, (void*)qkv,
                     OC_, L_, C_, (size_t)L_ * C_, (size_t)OC_ * L_, (size_t)0);
  hipLaunchKernelGGL(attn_kernel, dim3(8, HD_, B_), dim3(256), 0, stream,
                     (const __hip_bfloat16*)qkv, hT);
  // out = wpp @ hT^T + b_proj + x   (32x64 tiles, 512 blocks = 2/CU)
  hipLaunchKernelGGL((gemm_bt16_kernel<1, 2, false>),
                     dim3(L_ / 64, C_ / 32, B_), dim3(256), 0, stream,
                     wpp16, hT, b_proj, x, (void*)out,
                     C_, L_, C_, (size_t)L_ * C_, (size_t)C_ * L_, (size_t)C_ * L_);
}

// Round 22
// 47.581 us; speedup vs baseline: 1.2213x; 1.2213x over previous
//
#include <hip/hip_runtime.h>
#include <hip/hip_bf16.h>
#include <cstddef>
#include <cstdint>

#define B_ 2
#define C_ 512
#define L_ 1024
#define NH_ 8
#define HD_ 64
#define OC_ 1536  // 3*C

typedef short short8 __attribute__((ext_vector_type(8)));
typedef short short4v __attribute__((ext_vector_type(4)));
typedef float f32x4 __attribute__((ext_vector_type(4)));
typedef __fp16 f16x4 __attribute__((ext_vector_type(4)));
typedef __fp16 f16x2 __attribute__((ext_vector_type(2)));

__device__ inline float bf_bits_to_f32(unsigned short u) {
  union { unsigned u32; float f; } c; c.u32 = ((unsigned)u) << 16; return c.f;
}
__device__ inline short f32_to_bf_bits(float f) {
  union { float f; unsigned u; } c; c.f = f;
  return (short)((c.u + 0x7FFFu + ((c.u >> 16) & 1u)) >> 16);
}

// Fast 2^y on the VALU (Schraudolph): 2 full-rate VALU ops vs 1 quarter-rate
// v_exp_f32. r18-verified: absmax 0.03125 (threshold 0.101).
__device__ __forceinline__ float fexp2_fast(float y) {
  union { unsigned u; float f; } v;
  v.u = (unsigned)fmaf(y, 8388608.0f, 1065055000.0f);
  return v.f;
}

// async global->LDS, 16B per lane; LDS dest = wave-uniform base + lane*16.
__device__ __forceinline__ void gl2lds16(const short* g, short* l) {
  __builtin_amdgcn_global_load_lds(
      (const __attribute__((address_space(1))) unsigned*)(const void*)g,
      (__attribute__((address_space(3))) unsigned*)(void*)l, 16, 0, 0);
}

// ---------------------------------------------------------------------------
// K1 prep: blocks 0-511: BN stats -> s,t. 512-703: w_qkv -> bf16.
//          704-767: w_proj permuted cols -> bf16 (wpp[o][d*8+g]).
// ---------------------------------------------------------------------------
__global__ __launch_bounds__(256) void prep_kernel(
    const float* __restrict__ x, const float* __restrict__ gamma,
    const float* __restrict__ beta, const float* __restrict__ w_qkv,
    const float* __restrict__ w_proj,
    float* __restrict__ s_out, float* __restrict__ t_out,
    short* __restrict__ wq16, short* __restrict__ wpp16)
{
  const int bid = blockIdx.x;
  const int tid = threadIdx.x;
  if (bid < 512) {
    const int ch = bid;
    const float4 v0 = *(const float4*)(x + (size_t)ch * L_ + tid * 4);
    const float4 v1 = *(const float4*)(x + (size_t)(C_ + ch) * L_ + tid * 4);
    float s1 = v0.x + v0.y + v0.z + v0.w + v1.x + v1.y + v1.z + v1.w;
    float s2 = v0.x*v0.x + v0.y*v0.y + v0.z*v0.z + v0.w*v0.w
             + v1.x*v1.x + v1.y*v1.y + v1.z*v1.z + v1.w*v1.w;
    #pragma unroll
    for (int off = 32; off > 0; off >>= 1) {
      s1 += __shfl_down(s1, off);
      s2 += __shfl_down(s2, off);
    }
    __shared__ float r1[4], r2[4];
    const int wid = tid >> 6, lane = tid & 63;
    if (lane == 0) { r1[wid] = s1; r2[wid] = s2; }
    __syncthreads();
    if (tid == 0) {
      const float S1 = r1[0] + r1[1] + r1[2] + r1[3];
      const float S2 = r2[0] + r2[1] + r2[2] + r2[3];
      const float invN = 1.f / (float)(B_ * L_);
      const float mean = S1 * invN;
      const float var  = S2 * invN - mean * mean;  // biased
      const float rstd = rsqrtf(var + 1e-5f);
      const float sc = gamma[ch] * rstd;
      s_out[ch] = sc;
      t_out[ch] = beta[ch] - mean * sc;
    }
  } else if (bid < 704) {
    const int base = (bid - 512) * 4096 + tid * 16;
    #pragma unroll
    for (int it = 0; it < 2; ++it) {
      const float4 a0 = *(const float4*)(w_qkv + base + it * 8);
      const float4 a1 = *(const float4*)(w_qkv + base + it * 8 + 4);
      short8 v;
      v[0] = f32_to_bf_bits(a0.x); v[1] = f32_to_bf_bits(a0.y);
      v[2] = f32_to_bf_bits(a0.z); v[3] = f32_to_bf_bits(a0.w);
      v[4] = f32_to_bf_bits(a1.x); v[5] = f32_to_bf_bits(a1.y);
      v[6] = f32_to_bf_bits(a1.z); v[7] = f32_to_bf_bits(a1.w);
      *(short8*)(wq16 + base + it * 8) = v;
    }
  } else {
    // wpp[o][c'] = w[o][(c'&7)*64+(c'>>3)]
    #pragma unroll
    for (int grp = 0; grp < 4; ++grp) {
      const int idx = (bid - 704) * 4096 + tid * 16 + grp * 4;
      const int o = idx >> 9, cp = idx & 511;
      short4v v;
      #pragma unroll
      for (int j = 0; j < 4; ++j) {
        const int c = ((cp + j) & 7) * 64 + ((cp + j) >> 3);
        v[j] = f32_to_bf_bits(w_proj[(size_t)o * C_ + c]);
      }
      *(short4v*)(wpp16 + (size_t)o * C_ + cp) = v;
    }
  }
}

// ---------------------------------------------------------------------------
// K2: xT[b][t][c] = bf16(x[b][c][t]*s[c] + t[c])  (BN folded into transpose)
// ---------------------------------------------------------------------------
__global__ __launch_bounds__(256) void xt_kernel(
    const float* __restrict__ x, const float* __restrict__ s,
    const float* __restrict__ t, short* __restrict__ xT)
{
  __shared__ float T[64][65];
  const int t0 = blockIdx.x * 64, c0 = blockIdx.y * 64, b = blockIdx.z;
  const int tid = threadIdx.x;
  const float* xp = x + (size_t)b * C_ * L_;
  #pragma unroll
  for (int it = 0; it < 4; ++it) {
    const int idx = it * 256 + tid;
    const int rr = idx >> 4, c4 = (idx & 15) * 4;  // rr = c-local, c4 = t-local
    const float4 v = *(const float4*)(xp + (size_t)(c0 + rr) * L_ + t0 + c4);
    const float sc = s[c0 + rr], tc = t[c0 + rr];
    T[rr][c4 + 0] = fmaf(v.x, sc, tc);
    T[rr][c4 + 1] = fmaf(v.y, sc, tc);
    T[rr][c4 + 2] = fmaf(v.z, sc, tc);
    T[rr][c4 + 3] = fmaf(v.w, sc, tc);
  }
  __syncthreads();
  #pragma unroll
  for (int it = 0; it < 4; ++it) {
    const int idx = it * 256 + tid;
    const int tt_ = idx >> 4, cc4 = (idx & 15) * 4;
    short4v o;
    #pragma unroll
    for (int j = 0; j < 4; ++j) o[j] = f32_to_bf_bits(T[cc4 + j][tt_]);
    *(short4v*)(xT + ((size_t)b * L_ + t0 + tt_) * C_ + c0 + cc4) = o;
  }
}

// ---------------------------------------------------------------------------
// K3: bf16 MFMA GEMM, both operands row-major shared-K (r12 verbatim).
// ---------------------------------------------------------------------------
template <int MR, int NR, bool OUT_BF16>
__global__ __launch_bounds__(256) void gemm_bt16_kernel(
    const short* __restrict__ A, const short* __restrict__ B,
    const float* __restrict__ bias, const float* __restrict__ res,
    void* __restrict__ Cv, int M, int N, int K,
    size_t sB, size_t sC, size_t sR)
{
  constexpr int BM = MR * 32, BN = NR * 32;
  __shared__ short As[BM * 64];
  __shared__ short Bs[BN * 64];
  const int tid = threadIdx.x;
  const int l = tid & 63, w = tid >> 6;
  const int wr = w >> 1, wc = w & 1;
  const int ll = l & 15;
  const int n0 = blockIdx.x * BN, m0 = blockIdx.y * BM, bz = blockIdx.z;
  const short* Bg = B + (size_t)bz * sB;
  f32x4 acc[MR][NR] = {};

  for (int k0 = 0; k0 < K; k0 += 64) {
    #pragma unroll
    for (int it = 0; it < BM / 32; ++it) {
      const int row0 = w * (BM / 4) + it * 8;
      const int row = row0 + (l >> 3), sl = l & 7;
      gl2lds16(A + (size_t)(m0 + row) * K + k0 + ((sl ^ (row & 7)) * 8),
               As + row0 * 64);
    }
    #pragma unroll
    for (int it = 0; it < BN / 32; ++it) {
      const int row0 = w * (BN / 4) + it * 8;
      const int row = row0 + (l >> 3), sl = l & 7;
      gl2lds16(Bg + (size_t)(n0 + row) * K + k0 + ((sl ^ (row & 7)) * 8),
               Bs + row0 * 64);
    }
    __syncthreads();
    #pragma unroll
    for (int kk = 0; kk < 2; ++kk) {
      short8 af[MR], bfg[NR];
      const int sd = kk * 4 + (l >> 4);
      #pragma unroll
      for (int m = 0; m < MR; ++m) {
        const int ra = wr * MR * 16 + m * 16 + ll;
        af[m] = *(const short8*)(As + ra * 64 + (sd ^ (ra & 7)) * 8);
      }
      #pragma unroll
      for (int n = 0; n < NR; ++n) {
        const int rb = wc * NR * 16 + n * 16 + ll;
        bfg[n] = *(const short8*)(Bs + rb * 64 + (sd ^ (rb & 7)) * 8);
      }
      #pragma unroll
      for (int m = 0; m < MR; ++m)
        #pragma unroll
        for (int n = 0; n < NR; ++n)
          acc[m][n] = __builtin_amdgcn_mfma_f32_16x16x32_bf16(
              af[m], bfg[n], acc[m][n], 0, 0, 0);
    }
    __syncthreads();
  }

  const int rg4 = (l >> 4) * 4;
  __hip_bfloat16* Cb = (__hip_bfloat16*)Cv + (size_t)bz * sC;
  float* Cf = (float*)Cv + (size_t)bz * sC;
  const float* Rp = res + (size_t)bz * sR;
  #pragma unroll
  for (int m = 0; m < MR; ++m) {
    #pragma unroll
    for (int reg = 0; reg < 4; ++reg) {
      const int gm = m0 + wr * MR * 16 + m * 16 + rg4 + reg;
      const float bv = bias[gm];
      #pragma unroll
      for (int n = 0; n < NR; ++n) {
        const int gn = n0 + wc * NR * 16 + n * 16 + ll;
        float v = acc[m][n][reg] + bv;
        if (OUT_BF16) {
          Cb[(size_t)gm * N + gn] = __hip_bfloat16_raw{(unsigned short)f32_to_bf_bits(v)};
        } else {
          v += Rp[(size_t)gm * N + gn];
          Cf[(size_t)gm * N + gn] = v;
        }
      }
    }
  }
}

// ---------------------------------------------------------------------------
// K4: MFMA attention (r18 verbatim — the measured optimum).
// ---------------------------------------------------------------------------
__global__ __launch_bounds__(256, 4) void attn_kernel(
    const __hip_bfloat16* __restrict__ qkv, short* __restrict__ hT)
{
  __shared__ __fp16 Klds[1024 * 8];   // [f][g] f16, 16 KB (reused for O out)
  __shared__ __fp16 Vlds[9 * 1032];   // [9][1032] f16, padded rows

  const int tq = blockIdx.x, d = blockIdx.y, b = blockIdx.z;
  const int tid = threadIdx.x;
  const int w = tid >> 6, l = tid & 63;
  const int hi = l >> 4, ll = l & 15;
  const int t0 = tq * 128 + w * 32;
  const short* base = (const short*)qkv + (size_t)b * OC_ * L_;
  short* KldsS = (short*)Klds;
  short* VldsS = (short*)Vlds;

  // ---- stage K[f][g] as f16 (coalesced along f)
  #pragma unroll
  for (int it = 0; it < 4; ++it) {
    const int f = it * 256 + tid;
    unsigned u[4];
    #pragma unroll
    for (int e = 0; e < 4; ++e) {
      const f16x2 p = __builtin_amdgcn_cvt_pkrtz(
          bf_bits_to_f32((unsigned short)base[(size_t)((8 + 2*e)   * HD_ + d) * L_ + f]),
          bf_bits_to_f32((unsigned short)base[(size_t)((8 + 2*e+1) * HD_ + d) * L_ + f]));
      u[e] = __builtin_bit_cast(unsigned, p);
    }
    uint4 uu; uu.x = u[0]; uu.y = u[1]; uu.z = u[2]; uu.w = u[3];
    *(uint4*)(KldsS + f * 8) = uu;
  }
  // ---- stage V[g][f] as f16, padded rows (no swizzle)
  #pragma unroll
  for (int it = 0; it < 4; ++it) {
    const int i = it * 256 + tid;
    const int g = i >> 7, fs = i & 127;
    const short8 v = *(const short8*)(
        base + (size_t)((16 + g) * HD_ + d) * L_ + fs * 8);
    unsigned u[4];
    #pragma unroll
    for (int e = 0; e < 4; ++e) {
      const f16x2 p = __builtin_amdgcn_cvt_pkrtz(
          bf_bits_to_f32((unsigned short)v[2 * e]),
          bf_bits_to_f32((unsigned short)v[2 * e + 1]));
      u[e] = __builtin_bit_cast(unsigned, p);
    }
    uint4 uu; uu.x = u[0]; uu.y = u[1]; uu.z = u[2]; uu.w = u[3];
    *(uint4*)(VldsS + g * 1032 + fs * 8) = uu;
  }
  // ---- row 8 = ones (f16 1.0 = 0x3C00): denominator via MFMA
  {
    uint2 ones; ones.x = 0x3C003C00u; ones.y = 0x3C003C00u;
    *(uint2*)(VldsS + 8 * 1032 + tid * 4) = ones;
  }

  // ---- Q B-fragments (lanes l<32): B[k=4*hi+j][t], scale*log2e folded in
  f16x4 bQ[2] = {};
  if (l < 32) {
    const int g0 = 4 * hi;  // hi in {0,1}
    #pragma unroll
    for (int tt = 0; tt < 2; ++tt) {
      const int t = t0 + tt * 16 + ll;
      float q[4];
      #pragma unroll
      for (int j = 0; j < 4; ++j)
        q[j] = bf_bits_to_f32(
                   (unsigned short)base[(size_t)((g0 + j) * HD_ + d) * L_ + t]) *
               0.29448889f;  // 24^-0.5 * log2(e)
      const f16x2 a = __builtin_amdgcn_cvt_pkrtz(q[0], q[1]);
      const f16x2 bb = __builtin_amdgcn_cvt_pkrtz(q[2], q[3]);
      union { f16x4 v; uint2 u; } m;
      m.u.x = __builtin_bit_cast(unsigned, a);
      m.u.y = __builtin_bit_cast(unsigned, bb);
      bQ[tt] = m.v;
    }
  }

  __syncthreads();  // K/V staged

  const int vrow = (ll < 9) ? ll : 8;     // lane-constant PV A-row
  const f32x4 z4 = {0.f, 0.f, 0.f, 0.f};
  f32x4 accA[2] = {}, accB[2] = {};       // two independent PV chains per tt
  // K A-base: lanes hi>=2 (k=8..15, B-side zero) clamp to the hi&1 slot --
  // in-bounds, finite, annihilated by bQ zeros.
  const __fp16* akB = Klds + ll * 8 + 4 * (hi & 1);
  const __fp16* avB = Vlds + vrow * 1032 + 4 * hi;

  #pragma unroll
  for (int c = 0; c < 8; ++c) {
    #pragma unroll
    for (int ft = 0; ft < 8; ++ft) {
      const f16x4 ak = *(const f16x4*)(akB + c * 1024 + ft * 128);
      const f16x4 av = *(const f16x4*)(avB + c * 128 + ft * 16);
      #pragma unroll
      for (int tt = 0; tt < 2; ++tt) {
        const f32x4 s = __builtin_amdgcn_mfma_f32_16x16x16f16(
            ak, bQ[tt], z4, 0, 0, 0);
        const f16x2 p0 = __builtin_amdgcn_cvt_pkrtz(fexp2_fast(s[0]),
                                                    fexp2_fast(s[1]));
        const f16x2 p1 = __builtin_amdgcn_cvt_pkrtz(fexp2_fast(s[2]),
                                                    fexp2_fast(s[3]));
        union { f16x4 v; uint2 u; } bp;
        bp.u.x = __builtin_bit_cast(unsigned, p0);
        bp.u.y = __builtin_bit_cast(unsigned, p1);
        if (c & 1)
          accB[tt] = __builtin_amdgcn_mfma_f32_16x16x16f16(av, bp.v, accB[tt], 0, 0, 0);
        else
          accA[tt] = __builtin_amdgcn_mfma_f32_16x16x16f16(av, bp.v, accA[tt], 0, 0, 0);
      }
    }
  }

  // ---- epilogue: D row 8 (lane 32+ll, reg 0) = denominator; O out via LDS
  f32x4 accO[2];
  #pragma unroll
  for (int tt = 0; tt < 2; ++tt) accO[tt] = accA[tt] + accB[tt];

  __syncthreads();                 // all waves done with Klds
  short* Olds = KldsS;             // [128][8]
  #pragma unroll
  for (int nt = 0; nt < 2; ++nt) {
    const float sum = __shfl(accO[nt][0], 32 + ll);
    const float inv = 1.f / sum;
    if (hi < 2) {
      const int tl = w * 32 + nt * 16 + ll;
      #pragma unroll
      for (int reg = 0; reg < 4; ++reg)
        Olds[tl * 8 + hi * 4 + reg] = f32_to_bf_bits(accO[nt][reg] * inv);
    }
  }
  __syncthreads();
  if (tid < 128) {
    const short8 ov = *(const short8*)(Olds + tid * 8);
    *(short8*)(hT + ((size_t)b * L_ + tq * 128 + tid) * C_ + d * 8) = ov;
  }
}

// ---------------------------------------------------------------------------
extern "C" void kernel_launch(void* const* d_in, const int* in_sizes, int n_in,
                              void* d_out, int out_size, void* d_ws, size_t ws_size,
                              hipStream_t stream) {
  (void)in_sizes; (void)n_in; (void)out_size; (void)ws_size;
  const float* x      = (const float*)d_in[0];
  const float* gamma  = (const float*)d_in[1];
  const float* beta   = (const float*)d_in[2];
  const float* w_qkv  = (const float*)d_in[3];
  const float* b_qkv  = (const float*)d_in[4];
  const float* w_proj = (const float*)d_in[5];
  const float* b_proj = (const float*)d_in[6];
  float* out = (float*)d_out;
  char* wsb = (char*)d_ws;

  // workspace layout (bytes), ~12 MB
  float* s_buf = (float*)(wsb + 0);                         // 2 KB
  float* t_buf = (float*)(wsb + 2048);                      // 2 KB
  short* wq16  = (short*)(wsb + 4096);                      // 1.5 MB
  short* wpp16 = (short*)(wsb + 4096 + 1572864);            // 0.5 MB
  short* xT    = (short*)(wsb + 4096 + 2097152);            // 2 MB
  short* qkv   = (short*)(wsb + 4096 + 4194304);            // 6 MB
  short* hT    = (short*)(wsb + 4096 + 10485760);           // 2 MB

  hipLaunchKernelGGL(prep_kernel, dim3(768), dim3(256), 0, stream,
                     x, gamma, beta, w_qkv, w_proj, s_buf, t_buf, wq16, wpp16);
  hipLaunchKernelGGL(xt_kernel, dim3(L_ / 64, C_ / 64, B_), dim3(256), 0, stream,
                     x, s_buf, t_buf, xT);
  // qkv[o][t] = wq16 @ xn + b_qkv   (64x64 tiles, 768 blocks = 3/CU)
  hipLaunchKernelGGL((gemm_bt16_kernel<2, 2, true>),
                     dim3(L_ / 64, OC_ / 64, B_), dim3(256), 0, stream,
                     wq16, xT, b_qkv, (const float*)nullptr, (void*)qkv,
                     OC_, L_, C_, (size_t)L_ * C_, (size_t)OC_ * L_, (size_t)0);
  hipLaunchKernelGGL(attn_kernel, dim3(8, HD_, B_), dim3(256), 0, stream,
                     (const __hip_bfloat16*)qkv, hT);
  // out = wpp @ hT^T + b_proj + x   (32x64 tiles, 512 blocks = 2/CU)
  hipLaunchKernelGGL((gemm_bt16_kernel<1, 2, false>),
                     dim3(L_ / 64, C_ / 32, B_), dim3(256), 0, stream,
                     wpp16, hT, b_proj, x, (void*)out,
                     C_, L_, C_, (size_t)L_ * C_, (size_t)C_ * L_, (size_t)C_ * L_);
}